// Round 3
// baseline (371.563 us; speedup 1.0000x reference)
//
#include <hip/hip_runtime.h>
#include <math.h>

#define IMG_H 512
#define IMG_W 512
#define TS 32
#define NC 5
#define NB 8

__device__ __forceinline__ int reflect_idx(int i, int n) {
    if (i < 0) i = -i;
    if (i >= n) i = 2 * n - 2 - i;
    return i;
}

// ln(x) via native v_log_f32 (log2). rel err ~2^-21, fine vs 1.5e-2 tolerance.
__device__ __forceinline__ float fast_log(float x) {
    return __builtin_amdgcn_logf(x) * 0.6931471805599453f;
}

__device__ __forceinline__ float fast_asinh(float v) {
    float a = fabsf(v);
    float r = fast_log(a + __builtin_amdgcn_sqrtf(fmaf(a, a, 1.0f)));
    return copysignf(r, v);
}

// Heterogeneous kernel: blockIdx.x < 16  -> clahe tile pipeline (channel 3)
//                       blockIdx.x >= 16 -> pure streaming elementwise
//                                           (channels 0,1,2,4,5,6)
// Streaming blocks have no barriers/LDS use and keep HBM continuously busy,
// de-convoying the barrier-phased clahe blocks (whose LDS/VALU work hides
// under the streaming blocks' bandwidth time).
__global__ __launch_bounds__(256)
void imnorm_kernel(const float* __restrict__ img, const float* __restrict__ bgr,
                   const float* __restrict__ thr, const float* __restrict__ scl,
                   float* __restrict__ out)
{
    const int plane = blockIdx.z;          // b*NC + c
    const int c = plane % NC;
    const int bx = blockIdx.x;
    const int t = threadIdx.y * 32 + threadIdx.x;   // 0..255
    const size_t chs = (size_t)IMG_H * IMG_W;
    float* op = out + (size_t)plane * 7 * chs;

    if (bx >= 16) {
        // ================= streaming elementwise path =================
        const int w0s = (bx - 16) * TS;
        const int h0s = blockIdx.y * TS;
        const int row = t >> 3;            // 0..31
        const int col = (t & 7) * 4;       // 0,4,...,28

        const size_t base = (size_t)plane * chs + (size_t)(h0s + row) * IMG_W + (w0s + col);
        const float4 raw4 = *reinterpret_cast<const float4*>(img + base);
        const float4 bg4  = *reinterpret_cast<const float4*>(bgr + base);

        float s_thr[3], s_exp[3];
        #pragma unroll
        for (int j = 0; j < 3; ++j) {
            s_thr[j] = thr[c * 3 + j];
            s_exp[j] = __builtin_amdgcn_exp2f(scl[c * 3 + j] * 1.4426950408889634f);
        }

        const float rawa[4] = {raw4.x, raw4.y, raw4.z, raw4.w};
        const float bga[4]  = {bg4.x,  bg4.y,  bg4.z,  bg4.w};
        float o_l0[4], o_l1[4], o_a0[4], o_a1[4], o_a2[4];
        #pragma unroll
        for (int j = 0; j < 4; ++j) {
            float raw  = rawa[j];
            float off0 = (raw - bga[j]) * __builtin_amdgcn_rsqf(bga[j]);
            o_l0[j] = fast_log(fmaxf(off0 + 1.0f, 1.0f));   // t = 0
            o_l1[j] = fast_log(fmaxf(off0, 1.0f));          // t = 1: (off0-1)+1
            o_a0[j] = fast_asinh((raw - s_thr[0]) * s_exp[0]);
            o_a1[j] = fast_asinh((raw - s_thr[1]) * s_exp[1]);
            o_a2[j] = fast_asinh((raw - s_thr[2]) * s_exp[2]);
        }

        float* p = op + (size_t)(h0s + row) * IMG_W + (w0s + col);
        *reinterpret_cast<float4*>(p) = raw4;                                               // ch 0
        *reinterpret_cast<float4*>(p + 1 * chs) = make_float4(o_l0[0], o_l0[1], o_l0[2], o_l0[3]);
        *reinterpret_cast<float4*>(p + 2 * chs) = make_float4(o_l1[0], o_l1[1], o_l1[2], o_l1[3]);
        *reinterpret_cast<float4*>(p + 4 * chs) = make_float4(o_a0[0], o_a0[1], o_a0[2], o_a0[3]);
        *reinterpret_cast<float4*>(p + 5 * chs) = make_float4(o_a1[0], o_a1[1], o_a1[2], o_a1[3]);
        *reinterpret_cast<float4*>(p + 6 * chs) = make_float4(o_a2[0], o_a2[1], o_a2[2], o_a2[3]);
        return;
    }

    // ================= clahe tile path (channel 3 only) =================
    const int h0 = blockIdx.y * TS;
    const int w0 = bx * TS;
    const bool edge_w = (w0 == 0) || (w0 + TS == IMG_W);
    const bool edge_h = (h0 == 0) || (h0 + TS == IMG_H);

    const float* x = img + (size_t)plane * chs;

    __shared__ float xs[48][52];        // x tile + halo 8
    __shared__ float rs[40][44];        // res tile + halo 4
    __shared__ float pool[48 * 41];     // h1 48x41 overlaid with v2 32x44
    float (*h1)[41] = reinterpret_cast<float (*)[41]>(pool);  // dead after stage 3
    float (*v2)[44] = reinterpret_cast<float (*)[44]>(pool);  // born in stage 4

    // ---- stage 1: load x tile + halo ----
    if (!edge_w && !edge_h) {
        const float4* src4 = reinterpret_cast<const float4*>(
            x + (size_t)(h0 - 8) * IMG_W + (w0 - 8));
        #pragma unroll
        for (int k = 0; k < 3; ++k) {                   // 48*12 = 576 float4 tasks
            int i = t + k * 256;
            if (i < 576) {
                int r = i / 12, cc = i - r * 12;
                *reinterpret_cast<float4*>(&xs[r][cc * 4]) = src4[r * 128 + cc];
            }
        }
    } else {
        #pragma unroll
        for (int k = 0; k < 9; ++k) {                   // 48*48 = 9*256 scalar
            int i = t + k * 256;
            int r = i / 48, cc = i - r * 48;
            int gr = reflect_idx(h0 - 8 + r, IMG_H);
            int gc = reflect_idx(w0 - 8 + cc, IMG_W);
            xs[r][cc] = x[gr * IMG_W + gc];
        }
    }
    __syncthreads();

    // ---- stage 2: horizontal 9-sum of xs -> h1, sliding window ----
    if (t < 240) {                      // 48 rows x 5 segments of 8
        const int r  = t / 5;
        const int c0 = (t - r * 5) * 8;
        float s = xs[r][c0];
        #pragma unroll
        for (int d = 1; d < 9; ++d) s += xs[r][c0 + d];
        h1[r][c0] = s;
        #pragma unroll
        for (int k = 1; k < 8; ++k) {
            s += xs[r][c0 + 8 + k] - xs[r][c0 + k - 1];
            h1[r][c0 + k] = s;
        }
    }
    __syncthreads();

    // ---- stage 3: vertical 9-sum -> res over tile+halo4, sliding window ----
    if (t < 200) {                      // 40 cols x 5 row-segments of 8
        const int seg = t / 40;
        const int cl  = t - seg * 40;
        const int r0  = seg * 8;
        float s = h1[r0][cl];
        #pragma unroll
        for (int d = 1; d < 9; ++d) s += h1[r0 + d][cl];
        rs[r0][cl] = xs[r0 + 4][cl + 4] - s * (1.0f / 81.0f);
        #pragma unroll
        for (int k = 1; k < 8; ++k) {
            s += h1[r0 + 8 + k][cl] - h1[r0 + k - 1][cl];
            rs[r0 + k][cl] = xs[r0 + k + 4][cl + 4] - s * (1.0f / 81.0f);
        }
    }
    __syncthreads();

    // ---- stage 4: vertical 9-sum of res^2 -> v2, sliding ----
    if (t < 160) {                      // 40 cols x 4 row-segments of 8
        const int seg = t / 40;
        const int cl  = t - seg * 40;
        const int r0  = seg * 8;
        if (!edge_h) {
            float v = rs[r0][cl];
            float s = v * v;
            #pragma unroll
            for (int d = 1; d < 9; ++d) { v = rs[r0 + d][cl]; s = fmaf(v, v, s); }
            v2[r0][cl] = s;
            #pragma unroll
            for (int k = 1; k < 8; ++k) {
                float a = rs[r0 + 8 + k][cl];
                float b = rs[r0 + k - 1][cl];
                s = fmaf(a, a, fmaf(b, -b, s));
                v2[r0 + k][cl] = s;
            }
        } else {
            #pragma unroll
            for (int k = 0; k < 8; ++k) {
                const int hh = h0 + r0 + k;
                float s = 0.f;
                #pragma unroll
                for (int d = 0; d < 9; ++d) {
                    int mr = reflect_idx(hh - 4 + d, IMG_H) - (h0 - 4);  // [0,40)
                    float v = rs[mr][cl];
                    s = fmaf(v, v, s);
                }
                v2[r0 + k][cl] = s;
            }
        }
    }
    __syncthreads();

    // ---- stage 5: horizontal 9-sum of v2 + clahe output ----
    const int r5  = t >> 3;            // 0..31 output row
    const int wl0 = (t & 7) * 4;       // first output col

    float ssum[4];
    if (!edge_w) {
        const float* vr = &v2[r5][wl0];             // cols wl0..wl0+11 (w-4..w+7)
        float4 A  = *reinterpret_cast<const float4*>(vr);
        float4 Bv = *reinterpret_cast<const float4*>(vr + 4);
        float4 Cv = *reinterpret_cast<const float4*>(vr + 8);
        float s0 = ((A.x + A.y) + (A.z + A.w)) + ((Bv.x + Bv.y) + (Bv.z + Bv.w)) + Cv.x;
        ssum[0] = s0;
        ssum[1] = s0      - A.x + Cv.y;
        ssum[2] = ssum[1] - A.y + Cv.z;
        ssum[3] = ssum[2] - A.z + Cv.w;
    } else {
        #pragma unroll
        for (int j = 0; j < 4; ++j) {
            const int w = w0 + wl0 + j;
            float s = 0.f;
            #pragma unroll
            for (int d = 0; d < 9; ++d) {
                int mc = reflect_idx(w - 4 + d, IMG_W) - (w0 - 4);   // [0,40)
                s += v2[r5][mc];
            }
            ssum[j] = s;
        }
    }

    const float4 rsv = *reinterpret_cast<const float4*>(&rs[r5 + 4][wl0 + 4]);
    const float rsa[4] = {rsv.x, rsv.y, rsv.z, rsv.w};
    float o_cl[4];
    #pragma unroll
    for (int j = 0; j < 4; ++j) {
        float stdev = __builtin_amdgcn_sqrtf(fmaxf(ssum[j], 0.0f) * (1.0f / 81.0f));
        o_cl[j] = rsa[j] * __builtin_amdgcn_rcpf(fmaxf(stdev, 1.0f));
    }

    float* p = op + 3 * chs + (size_t)(h0 + r5) * IMG_W + (w0 + wl0);
    *reinterpret_cast<float4*>(p) = make_float4(o_cl[0], o_cl[1], o_cl[2], o_cl[3]);
}

extern "C" void kernel_launch(void* const* d_in, const int* in_sizes, int n_in,
                              void* d_out, int out_size, void* d_ws, size_t ws_size,
                              hipStream_t stream) {
    const float* img = (const float*)d_in[0];
    const float* bg  = (const float*)d_in[1];
    const float* thr = (const float*)d_in[2];
    const float* scl = (const float*)d_in[3];
    float* out = (float*)d_out;

    // x: 0..15 clahe tiles, 16..31 streaming elementwise tiles
    dim3 grid(32, IMG_H / TS, NB * NC);   // 32 x 16 x 40 = 20480 blocks
    dim3 block(32, 8);
    hipLaunchKernelGGL(imnorm_kernel, grid, block, 0, stream,
                       img, bg, thr, scl, out);
}

// Round 4
// 365.330 us; speedup vs baseline: 1.0171x; 1.0171x over previous
//
#include <hip/hip_runtime.h>
#include <math.h>

#define IMG_H 512
#define IMG_W 512
#define TS 32
#define NC 5
#define NB 8
#define CHS (IMG_H * IMG_W)      // 262144 floats per channel-plane
#define CHS4 (CHS / 4)           // 65536 float4s per channel-plane

__device__ __forceinline__ int reflect_idx(int i, int n) {
    if (i < 0) i = -i;
    if (i >= n) i = 2 * n - 2 - i;
    return i;
}

// ln(x) via native v_log_f32 (log2). rel err ~2^-21, fine vs 1.5e-2 tolerance.
__device__ __forceinline__ float fast_log(float x) {
    return __builtin_amdgcn_logf(x) * 0.6931471805599453f;
}

__device__ __forceinline__ float fast_asinh(float v) {
    float a = fabsf(v);
    float r = fast_log(a + __builtin_amdgcn_sqrtf(fmaf(a, a, 1.0f)));
    return copysignf(r, v);
}

// ======================= kernel 1: clahe (channel 3) =======================
__global__ __launch_bounds__(256)
void clahe_kernel(const float* __restrict__ img, float* __restrict__ out)
{
    const int plane = blockIdx.z;          // b*NC + c
    const int h0 = blockIdx.y * TS;
    const int w0 = blockIdx.x * TS;
    const bool edge_w = (w0 == 0) || (w0 + TS == IMG_W);
    const bool edge_h = (h0 == 0) || (h0 + TS == IMG_H);

    const float* x = img + (size_t)plane * CHS;
    const int t = threadIdx.y * 32 + threadIdx.x;   // 0..255

    __shared__ float xs[48][48];        // x tile + halo 8 (contiguous; col reads 2-way = free)
    __shared__ float rs[40][44];        // res tile + halo 4
    __shared__ float pool[48 * 41];     // h1 48x41 overlaid with v2 32x44
    float (*h1)[41] = reinterpret_cast<float (*)[41]>(pool);  // dead after stage 3
    float (*v2)[44] = reinterpret_cast<float (*)[44]>(pool);  // born in stage 4

    // ---- stage 1: load x tile + halo ----
    if (!edge_w && !edge_h) {
        const float4* src4 = reinterpret_cast<const float4*>(
            x + (size_t)(h0 - 8) * IMG_W + (w0 - 8));       // (w0-8)%4==0 -> aligned
        #pragma unroll
        for (int k = 0; k < 3; ++k) {                       // 48*12 = 576 float4 tasks
            int i = t + k * 256;
            if (i < 576) {
                int r = i / 12, cc = i - r * 12;
                *reinterpret_cast<float4*>(&xs[r][cc * 4]) = src4[r * 128 + cc];
            }
        }
    } else {
        #pragma unroll
        for (int k = 0; k < 9; ++k) {                       // 48*48 scalar w/ reflect
            int i = t + k * 256;
            int r = i / 48, cc = i - r * 48;
            int gr = reflect_idx(h0 - 8 + r, IMG_H);
            int gc = reflect_idx(w0 - 8 + cc, IMG_W);
            xs[r][cc] = x[gr * IMG_W + gc];
        }
    }
    __syncthreads();

    // ---- stage 2: horizontal 9-sum of xs -> h1, sliding window ----
    if (t < 240) {                      // 48 rows x 5 segments of 8
        const int r  = t / 5;
        const int c0 = (t - r * 5) * 8;
        float s = xs[r][c0];
        #pragma unroll
        for (int d = 1; d < 9; ++d) s += xs[r][c0 + d];
        h1[r][c0] = s;
        #pragma unroll
        for (int k = 1; k < 8; ++k) {
            s += xs[r][c0 + 8 + k] - xs[r][c0 + k - 1];
            h1[r][c0 + k] = s;
        }
    }
    __syncthreads();

    // ---- stage 3: vertical 9-sum -> res over tile+halo4, sliding window ----
    if (t < 200) {                      // 40 cols x 5 row-segments of 8
        const int seg = t / 40;
        const int cl  = t - seg * 40;
        const int r0  = seg * 8;
        float s = h1[r0][cl];
        #pragma unroll
        for (int d = 1; d < 9; ++d) s += h1[r0 + d][cl];
        rs[r0][cl] = xs[r0 + 4][cl + 4] - s * (1.0f / 81.0f);
        #pragma unroll
        for (int k = 1; k < 8; ++k) {
            s += h1[r0 + 8 + k][cl] - h1[r0 + k - 1][cl];
            rs[r0 + k][cl] = xs[r0 + k + 4][cl + 4] - s * (1.0f / 81.0f);
        }
    }
    __syncthreads();

    // ---- stage 4: vertical 9-sum of res^2 -> v2 (overlays h1), sliding ----
    if (t < 160) {                      // 40 cols x 4 row-segments of 8
        const int seg = t / 40;
        const int cl  = t - seg * 40;
        const int r0  = seg * 8;
        if (!edge_h) {
            float v = rs[r0][cl];
            float s = v * v;
            #pragma unroll
            for (int d = 1; d < 9; ++d) { v = rs[r0 + d][cl]; s = fmaf(v, v, s); }
            v2[r0][cl] = s;
            #pragma unroll
            for (int k = 1; k < 8; ++k) {
                float a = rs[r0 + 8 + k][cl];
                float b = rs[r0 + k - 1][cl];
                s = fmaf(a, a, fmaf(b, -b, s));
                v2[r0 + k][cl] = s;
            }
        } else {
            #pragma unroll
            for (int k = 0; k < 8; ++k) {
                const int hh = h0 + r0 + k;
                float s = 0.f;
                #pragma unroll
                for (int d = 0; d < 9; ++d) {
                    int mr = reflect_idx(hh - 4 + d, IMG_H) - (h0 - 4);  // [0,40)
                    float v = rs[mr][cl];
                    s = fmaf(v, v, s);
                }
                v2[r0 + k][cl] = s;
            }
        }
    }
    __syncthreads();

    // ---- stage 5: horizontal 9-sum of v2 + clahe output ----
    const int r5  = t >> 3;            // 0..31 output row
    const int wl0 = (t & 7) * 4;       // first output col

    float ssum[4];
    if (!edge_w) {
        const float* vr = &v2[r5][wl0];             // cols wl0..wl0+11 (w-4..w+7)
        float4 A  = *reinterpret_cast<const float4*>(vr);
        float4 Bv = *reinterpret_cast<const float4*>(vr + 4);
        float4 Cv = *reinterpret_cast<const float4*>(vr + 8);
        float s0 = ((A.x + A.y) + (A.z + A.w)) + ((Bv.x + Bv.y) + (Bv.z + Bv.w)) + Cv.x;
        ssum[0] = s0;
        ssum[1] = s0      - A.x + Cv.y;
        ssum[2] = ssum[1] - A.y + Cv.z;
        ssum[3] = ssum[2] - A.z + Cv.w;
    } else {
        #pragma unroll
        for (int j = 0; j < 4; ++j) {
            const int w = w0 + wl0 + j;
            float s = 0.f;
            #pragma unroll
            for (int d = 0; d < 9; ++d) {
                int mc = reflect_idx(w - 4 + d, IMG_W) - (w0 - 4);   // [0,40)
                s += v2[r5][mc];
            }
            ssum[j] = s;
        }
    }

    const float4 rsv = *reinterpret_cast<const float4*>(&rs[r5 + 4][wl0 + 4]);
    const float rsa[4] = {rsv.x, rsv.y, rsv.z, rsv.w};
    float o_cl[4];
    #pragma unroll
    for (int j = 0; j < 4; ++j) {
        float stdev = __builtin_amdgcn_sqrtf(fmaxf(ssum[j], 0.0f) * (1.0f / 81.0f));
        o_cl[j] = rsa[j] * __builtin_amdgcn_rcpf(fmaxf(stdev, 1.0f));
    }

    float* p = out + ((size_t)plane * 7 + 3) * CHS + (size_t)(h0 + r5) * IMG_W + (w0 + wl0);
    *reinterpret_cast<float4*>(p) = make_float4(o_cl[0], o_cl[1], o_cl[2], o_cl[3]);
}

// ============ kernel 2: streaming elementwise (channels 0,1,2,4,5,6) ============
// Fully linear 1D over the 40 input planes; structurally identical to the
// rocclr fill kernel (which sustains 6.4 TB/s): float4 in, float4 out,
// no LDS, no barriers.
#define STREAM_BLOCKS 2560
#define STREAM_ITERS  4          // 2560*256*4 = 2,621,440 float4s = whole input

__global__ __launch_bounds__(256)
void stream_kernel(const float* __restrict__ img, const float* __restrict__ bgr,
                   const float* __restrict__ thr, const float* __restrict__ scl,
                   float* __restrict__ out)
{
    const int tid4 = blockIdx.x * 256 + threadIdx.x;     // 0..655359
    // stride per iteration = 655360 float4s = 10 whole planes -> channel c
    // is invariant across iterations for a given thread.
    const int c = (tid4 >> 16) % NC;

    float s_thr[3], s_exp[3];
    #pragma unroll
    for (int j = 0; j < 3; ++j) {
        s_thr[j] = thr[c * 3 + j];
        s_exp[j] = __builtin_amdgcn_exp2f(scl[c * 3 + j] * 1.4426950408889634f);
    }

    const float4* in4 = reinterpret_cast<const float4*>(img);
    const float4* bg4 = reinterpret_cast<const float4*>(bgr);
    float4* out4 = reinterpret_cast<float4*>(out);

    #pragma unroll
    for (int k = 0; k < STREAM_ITERS; ++k) {
        const int idx4 = tid4 + k * (STREAM_BLOCKS * 256);
        const int plane = idx4 >> 16;            // / CHS4
        const int within4 = idx4 & (CHS4 - 1);

        const float4 raw4 = in4[idx4];
        const float4 bgv4 = bg4[idx4];

        const float rawa[4] = {raw4.x, raw4.y, raw4.z, raw4.w};
        const float bga[4]  = {bgv4.x, bgv4.y, bgv4.z, bgv4.w};
        float o_l0[4], o_l1[4], o_a0[4], o_a1[4], o_a2[4];
        #pragma unroll
        for (int j = 0; j < 4; ++j) {
            float raw  = rawa[j];
            float off0 = (raw - bga[j]) * __builtin_amdgcn_rsqf(bga[j]);
            o_l0[j] = fast_log(fmaxf(off0 + 1.0f, 1.0f));   // t = 0
            o_l1[j] = fast_log(fmaxf(off0, 1.0f));          // t = 1: (off0-1)+1
            o_a0[j] = fast_asinh((raw - s_thr[0]) * s_exp[0]);
            o_a1[j] = fast_asinh((raw - s_thr[1]) * s_exp[1]);
            o_a2[j] = fast_asinh((raw - s_thr[2]) * s_exp[2]);
        }

        float4* p = out4 + (size_t)plane * 7 * CHS4 + within4;
        p[0 * CHS4] = raw4;
        p[1 * CHS4] = make_float4(o_l0[0], o_l0[1], o_l0[2], o_l0[3]);
        p[2 * CHS4] = make_float4(o_l1[0], o_l1[1], o_l1[2], o_l1[3]);
        p[4 * CHS4] = make_float4(o_a0[0], o_a0[1], o_a0[2], o_a0[3]);
        p[5 * CHS4] = make_float4(o_a1[0], o_a1[1], o_a1[2], o_a1[3]);
        p[6 * CHS4] = make_float4(o_a2[0], o_a2[1], o_a2[2], o_a2[3]);
    }
}

extern "C" void kernel_launch(void* const* d_in, const int* in_sizes, int n_in,
                              void* d_out, int out_size, void* d_ws, size_t ws_size,
                              hipStream_t stream) {
    const float* img = (const float*)d_in[0];
    const float* bg  = (const float*)d_in[1];
    const float* thr = (const float*)d_in[2];
    const float* scl = (const float*)d_in[3];
    float* out = (float*)d_out;

    // clahe first: warms img into L3 for the streaming kernel's re-read
    hipLaunchKernelGGL(clahe_kernel, dim3(IMG_W / TS, IMG_H / TS, NB * NC),
                       dim3(32, 8), 0, stream, img, out);
    hipLaunchKernelGGL(stream_kernel, dim3(STREAM_BLOCKS), dim3(256), 0, stream,
                       img, bg, thr, scl, out);
}

// Round 5
// 352.978 us; speedup vs baseline: 1.0527x; 1.0350x over previous
//
#include <hip/hip_runtime.h>
#include <math.h>

#define IMG_H 512
#define IMG_W 512
#define TS 32
#define NC 5
#define NB 8
#define CHS ((size_t)IMG_H * IMG_W)

typedef float f32x4 __attribute__((ext_vector_type(4)));

__device__ __forceinline__ int reflect_idx(int i, int n) {
    if (i < 0) i = -i;
    if (i >= n) i = 2 * n - 2 - i;
    return i;
}

// ln(x) via native v_log_f32 (log2). rel err ~2^-21, fine vs 1.5e-2 tolerance.
__device__ __forceinline__ float fast_log(float x) {
    return __builtin_amdgcn_logf(x) * 0.6931471805599453f;
}

__device__ __forceinline__ float fast_asinh(float v) {
    float a = fabsf(v);
    float r = fast_log(a + __builtin_amdgcn_sqrtf(fmaf(a, a, 1.0f)));
    return copysignf(r, v);
}

// output is write-once / never re-read: bypass L2 allocation
__device__ __forceinline__ void nt_store4(float* p, float a, float b, float c, float d) {
    f32x4 v = {a, b, c, d};
    __builtin_nontemporal_store(v, reinterpret_cast<f32x4*>(p));
}

__device__ __forceinline__ f32x4 nt_load4(const float* p) {
    return __builtin_nontemporal_load(reinterpret_cast<const f32x4*>(p));
}

__global__ __launch_bounds__(256)
void imnorm_kernel(const float* __restrict__ img, const float* __restrict__ bgr,
                   const float* __restrict__ thr, const float* __restrict__ scl,
                   float* __restrict__ out)
{
    const int plane = blockIdx.z;          // b*NC + c
    const int c = plane % NC;
    const int h0 = blockIdx.y * TS;
    const int w0 = blockIdx.x * TS;
    // reflection only possible in first/last block row/col (halo 8 < TS)
    const bool edge_w = (w0 == 0) || (w0 + TS == IMG_W);
    const bool edge_h = (h0 == 0) || (h0 + TS == IMG_H);

    const float* x  = img + plane * CHS;
    const float* bg = bgr + plane * CHS;
    float* op = out + plane * 7 * CHS;

    const int t = threadIdx.y * 32 + threadIdx.x;   // 0..255

    __shared__ float xs[48][48];        // x tile + halo 8 (192B row stride, 16B-aligned quads)
    __shared__ float rs[40][44];        // res tile + halo 4
    __shared__ float pool[48 * 41];     // h1 48x41 overlaid with v2 32x44
    float (*h1)[41] = reinterpret_cast<float (*)[41]>(pool);  // dead after stage 3
    float (*v2)[44] = reinterpret_cast<float (*)[44]>(pool);  // born in stage 4

    // output ownership: 1 row x 4 consecutive cols per thread
    const int r5  = t >> 3;            // 0..31 output row
    const int wl0 = (t & 7) * 4;       // 0,4,...,28 first output col

    // prefetch bg early (single-use -> nontemporal); latency hides under stage 1
    const f32x4 bgv = nt_load4(bg + (size_t)(h0 + r5) * IMG_W + (w0 + wl0));

    // per-channel constants (15 floats, L2-resident)
    float s_thr[3], s_exp[3];
    #pragma unroll
    for (int j = 0; j < 3; ++j) {
        s_thr[j] = thr[c * 3 + j];
        s_exp[j] = __builtin_amdgcn_exp2f(scl[c * 3 + j] * 1.4426950408889634f);
    }

    // ---- stage 1: load x tile + halo into LDS ----
    if (!edge_w && !edge_h) {
        const float4* src4 = reinterpret_cast<const float4*>(
            x + (size_t)(h0 - 8) * IMG_W + (w0 - 8));       // (w0-8)%4==0 -> aligned
        #pragma unroll
        for (int k = 0; k < 3; ++k) {                       // 48 rows x 12 float4 = 576 tasks
            int i = t + k * 256;
            if (i < 576) {
                int r = i / 12, cc = i - r * 12;
                *reinterpret_cast<float4*>(&xs[r][cc * 4]) = src4[r * 128 + cc];
            }
        }
    } else {
        #pragma unroll
        for (int k = 0; k < 9; ++k) {                       // 48*48 scalar w/ reflect
            int i = t + k * 256;
            int r = i / 48, cc = i - r * 48;
            int gr = reflect_idx(h0 - 8 + r, IMG_H);
            int gc = reflect_idx(w0 - 8 + cc, IMG_W);
            xs[r][cc] = x[gr * IMG_W + gc];
        }
    }
    __syncthreads();

    // ---- stage 1.5: elementwise channels 0,1,2,4,5,6 FIRST ----
    // 86% of the write traffic issues here and drains to HBM underneath the
    // entire stage-2..5 LDS pipeline (instead of bursting after it).
    {
        const float4 raw4 = *reinterpret_cast<const float4*>(&xs[r5 + 8][wl0 + 8]);
        const float rawa[4] = {raw4.x, raw4.y, raw4.z, raw4.w};
        const float bga[4]  = {bgv.x,  bgv.y,  bgv.z,  bgv.w};
        float o_l0[4], o_l1[4], o_a0[4], o_a1[4], o_a2[4];
        #pragma unroll
        for (int j = 0; j < 4; ++j) {
            float raw  = rawa[j];
            float off0 = (raw - bga[j]) * __builtin_amdgcn_rsqf(bga[j]);
            o_l0[j] = fast_log(fmaxf(off0 + 1.0f, 1.0f));   // t = 0
            o_l1[j] = fast_log(fmaxf(off0, 1.0f));          // t = 1: (off0-1)+1
            o_a0[j] = fast_asinh((raw - s_thr[0]) * s_exp[0]);
            o_a1[j] = fast_asinh((raw - s_thr[1]) * s_exp[1]);
            o_a2[j] = fast_asinh((raw - s_thr[2]) * s_exp[2]);
        }
        float* p = op + (size_t)(h0 + r5) * IMG_W + (w0 + wl0);
        nt_store4(p,           rawa[0], rawa[1], rawa[2], rawa[3]);   // ch 0
        nt_store4(p + 1 * CHS, o_l0[0], o_l0[1], o_l0[2], o_l0[3]);   // ch 1
        nt_store4(p + 2 * CHS, o_l1[0], o_l1[1], o_l1[2], o_l1[3]);   // ch 2
        nt_store4(p + 4 * CHS, o_a0[0], o_a0[1], o_a0[2], o_a0[3]);   // ch 4
        nt_store4(p + 5 * CHS, o_a1[0], o_a1[1], o_a1[2], o_a1[3]);   // ch 5
        nt_store4(p + 6 * CHS, o_a2[0], o_a2[1], o_a2[2], o_a2[3]);   // ch 6
    }

    // ---- stage 2: horizontal 9-sum of xs -> h1, sliding window ----
    if (t < 240) {                      // 48 rows x 5 segments of 8
        const int r  = t / 5;
        const int c0 = (t - r * 5) * 8;
        float s = xs[r][c0];
        #pragma unroll
        for (int d = 1; d < 9; ++d) s += xs[r][c0 + d];
        h1[r][c0] = s;
        #pragma unroll
        for (int k = 1; k < 8; ++k) {
            s += xs[r][c0 + 8 + k] - xs[r][c0 + k - 1];
            h1[r][c0 + k] = s;
        }
    }
    __syncthreads();

    // ---- stage 3: vertical 9-sum -> res over tile+halo4, sliding window ----
    if (t < 200) {                      // 40 cols x 5 row-segments of 8
        const int seg = t / 40;
        const int cl  = t - seg * 40;
        const int r0  = seg * 8;
        float s = h1[r0][cl];
        #pragma unroll
        for (int d = 1; d < 9; ++d) s += h1[r0 + d][cl];
        rs[r0][cl] = xs[r0 + 4][cl + 4] - s * (1.0f / 81.0f);
        #pragma unroll
        for (int k = 1; k < 8; ++k) {
            s += h1[r0 + 8 + k][cl] - h1[r0 + k - 1][cl];
            rs[r0 + k][cl] = xs[r0 + k + 4][cl + 4] - s * (1.0f / 81.0f);
        }
    }
    __syncthreads();

    // ---- stage 4: vertical 9-sum of res^2 -> v2 (overlays h1), sliding ----
    if (t < 160) {                      // 40 cols x 4 row-segments of 8
        const int seg = t / 40;
        const int cl  = t - seg * 40;
        const int r0  = seg * 8;
        if (!edge_h) {
            float v = rs[r0][cl];
            float s = v * v;
            #pragma unroll
            for (int d = 1; d < 9; ++d) { v = rs[r0 + d][cl]; s = fmaf(v, v, s); }
            v2[r0][cl] = s;
            #pragma unroll
            for (int k = 1; k < 8; ++k) {
                float a = rs[r0 + 8 + k][cl];
                float b = rs[r0 + k - 1][cl];
                s = fmaf(a, a, fmaf(b, -b, s));
                v2[r0 + k][cl] = s;
            }
        } else {
            #pragma unroll
            for (int k = 0; k < 8; ++k) {
                const int hh = h0 + r0 + k;
                float s = 0.f;
                #pragma unroll
                for (int d = 0; d < 9; ++d) {
                    int mr = reflect_idx(hh - 4 + d, IMG_H) - (h0 - 4);  // [0,40)
                    float v = rs[mr][cl];
                    s = fmaf(v, v, s);
                }
                v2[r0 + k][cl] = s;
            }
        }
    }
    __syncthreads();

    // ---- stage 5: horizontal 9-sum of v2 + clahe (channel 3) ----
    float ssum[4];
    if (!edge_w) {
        const float* vr = &v2[r5][wl0];             // cols wl0..wl0+11 (w-4..w+7)
        float4 A  = *reinterpret_cast<const float4*>(vr);
        float4 Bv = *reinterpret_cast<const float4*>(vr + 4);
        float4 Cv = *reinterpret_cast<const float4*>(vr + 8);
        float s0 = ((A.x + A.y) + (A.z + A.w)) + ((Bv.x + Bv.y) + (Bv.z + Bv.w)) + Cv.x;
        ssum[0] = s0;
        ssum[1] = s0      - A.x + Cv.y;
        ssum[2] = ssum[1] - A.y + Cv.z;
        ssum[3] = ssum[2] - A.z + Cv.w;
    } else {
        #pragma unroll
        for (int j = 0; j < 4; ++j) {
            const int w = w0 + wl0 + j;
            float s = 0.f;
            #pragma unroll
            for (int d = 0; d < 9; ++d) {
                int mc = reflect_idx(w - 4 + d, IMG_W) - (w0 - 4);   // [0,40)
                s += v2[r5][mc];
            }
            ssum[j] = s;
        }
    }

    const float4 rsv = *reinterpret_cast<const float4*>(&rs[r5 + 4][wl0 + 4]);
    const float rsa[4] = {rsv.x, rsv.y, rsv.z, rsv.w};
    float o_cl[4];
    #pragma unroll
    for (int j = 0; j < 4; ++j) {
        float stdev = __builtin_amdgcn_sqrtf(fmaxf(ssum[j], 0.0f) * (1.0f / 81.0f));
        o_cl[j] = rsa[j] * __builtin_amdgcn_rcpf(fmaxf(stdev, 1.0f));
    }

    float* p3 = op + 3 * CHS + (size_t)(h0 + r5) * IMG_W + (w0 + wl0);
    nt_store4(p3, o_cl[0], o_cl[1], o_cl[2], o_cl[3]);
}

extern "C" void kernel_launch(void* const* d_in, const int* in_sizes, int n_in,
                              void* d_out, int out_size, void* d_ws, size_t ws_size,
                              hipStream_t stream) {
    const float* img = (const float*)d_in[0];
    const float* bg  = (const float*)d_in[1];
    const float* thr = (const float*)d_in[2];
    const float* scl = (const float*)d_in[3];
    float* out = (float*)d_out;

    dim3 grid(IMG_W / TS, IMG_H / TS, NB * NC);   // 16 x 16 x 40 = 10240 blocks
    dim3 block(32, 8);
    hipLaunchKernelGGL(imnorm_kernel, grid, block, 0, stream,
                       img, bg, thr, scl, out);
}